// Round 7
// baseline (106.690 us; speedup 1.0000x reference)
//
#include <hip/hip_runtime.h>
#include <hip/hip_bf16.h>
#include <hip/hip_fp16.h>

// Problem: B=8192, T=128, D=7, I=128, C=10, H=64, L=128
// R21 = R20 with the attnB index bug fixed (uint2 stride: row*32+tg4, NOT
// row*64+tg4*2 — uint2 is 4 halves; R20 read OOB for rows>=4096) + phase-1
// af loads moved in-loop to fit the (256,6) VGPR cap (~84) without spill.
//  - main: grid 2048 = (bg2 0..63 x tg4 0..31), 128 rows x 4 trees/block
//    (m-rows 896=32*28 exact). LDS 18 KB (zsl 8K + lpt 10K);
//    launch_bounds(256,6) -> 6 blocks/CU = 24 waves/CU (75% occ cap).
//  - lpt reg-staged into LDS before phase-1 MFMAs (ds_write after, ONE
//    barrier) -> it-loop B-frags at ds_read latency, not L2.
//  - XCD swizzle bijective: bg2=(phys&7)*8+(phys>>8), tg4=(phys>>3)&31.
//  - prep unchanged (R19-verified).
// ws layout (float slots):
//   attnB fp16 [8192][128] off 0        (524288)
//   LPb   uint4 compact    off 524288   (81920)   [t][s][n<10][hf]
//   xbf   bf16 [8192][128] off 606208   (524288)
//   mbf   bf16 [896][128]  off 1130496  (57344)

#define BB 8192
#define TT 128
#define II 128
#define CC 10
#define HH 64

#define OFF_LPB 524288
#define OFF_XBF 606208
#define OFF_MBF 1130496

typedef __attribute__((ext_vector_type(8))) short short8;
typedef __attribute__((ext_vector_type(16))) float floatx16;

static __device__ inline unsigned int pkbf(float lo, float hi) {
  __hip_bfloat162 h = __float22bfloat162_rn(make_float2(lo, hi));
  unsigned int u;
  __builtin_memcpy(&u, &h, 4);
  return u;
}

static __device__ inline unsigned int pkh(float lo, float hi) {
  __half2 h = __float22half2_rn(make_float2(lo, hi));
  unsigned int u;
  __builtin_memcpy(&u, &h, 4);
  return u;
}

static __device__ inline short8 cvt8(float4 a, float4 b) {
  union { short8 v; unsigned int u[4]; } r;
  r.u[0] = pkbf(a.x, a.y);
  r.u[1] = pkbf(a.z, a.w);
  r.u[2] = pkbf(b.x, b.y);
  r.u[3] = pkbf(b.z, b.w);
  return r.v;
}

// ---- prep: 708 blocks x 64 thr (R19-verified) ------------------------------
// [0,256): attn, 32 rows/block (one wave)
// [256,384): leaf softmax, 1 tree/block
// [384,640): x f32->bf16, 4096 elems/block
// [640,668): mask f32->bf16, 4096 elems/block
// [668,708): zero out, 512 float4/block
__global__ __launch_bounds__(64) void prep_kernel(
    const float* __restrict__ x, const float* __restrict__ mask,
    const float* __restrict__ lo,
    const float* __restrict__ W1, const float* __restrict__ b1,
    const float* __restrict__ W2, const float* __restrict__ b2,
    __half* __restrict__ attnB, unsigned int* __restrict__ lpbG,
    unsigned short* __restrict__ xbf, unsigned short* __restrict__ mbf,
    float* __restrict__ out) {
  __shared__ __align__(16) char smem_raw[6144];
  const int blk = blockIdx.x;
  const int lane = threadIdx.x;           // 0..63 (one wave)
  const int half = lane >> 5, l31 = lane & 31;

  if (blk < 256) {
    // ---------------- attn: 32 rows, one wave -------------------------------
    const int b0 = blk * 32;

    short8 axf[8];
    const float* xrow = x + (size_t)(b0 + l31) * II + half * 8;
#pragma unroll
    for (int s = 0; s < 8; ++s)
      axf[s] = cvt8(*(const float4*)(xrow + s * 16),
                    *(const float4*)(xrow + s * 16 + 4));

    floatx16 acch[2];
#pragma unroll
    for (int i = 0; i < 16; ++i) { acch[0][i] = 0.f; acch[1][i] = 0.f; }
#pragma unroll
    for (int s = 0; s < 8; ++s) {
#pragma unroll
      for (int tile = 0; tile < 2; ++tile) {
        union { short8 v; unsigned int u[4]; } wf;
#pragma unroll
        for (int jp = 0; jp < 4; ++jp) {
          int k0 = s * 16 + half * 8 + jp * 2;
          float f0 = W1[(size_t)k0 * HH + tile * 32 + l31];
          float f1 = W1[(size_t)(k0 + 1) * HH + tile * 32 + l31];
          wf.u[jp] = pkbf(f0, f1);
        }
        acch[tile] = __builtin_amdgcn_mfma_f32_32x32x16_bf16(
            axf[s], wf.v, acch[tile], 0, 0, 0);
      }
    }
    __hip_bfloat16* hids = (__hip_bfloat16*)smem_raw;   // [32][72]
#pragma unroll
    for (int tile = 0; tile < 2; ++tile) {
      float bh = b1[tile * 32 + l31];
#pragma unroll
      for (int r = 0; r < 16; ++r) {
        int row = (r & 3) + 8 * (r >> 2) + 4 * half;
        hids[row * 72 + tile * 32 + l31] =
            __float2bfloat16(fmaxf(acch[tile][r] + bh, 0.f));
      }
    }
    __syncthreads();

    short8 ahf[4];
#pragma unroll
    for (int s = 0; s < 4; ++s)
      ahf[s] = *(const short8*)(hids + l31 * 72 + s * 16 + half * 8);

    floatx16 accl[4];
#pragma unroll
    for (int tile = 0; tile < 4; ++tile) {
#pragma unroll
      for (int i = 0; i < 16; ++i) accl[tile][i] = 0.f;
#pragma unroll
      for (int s = 0; s < 4; ++s) {
        union { short8 v; unsigned int u[4]; } wf;
#pragma unroll
        for (int jp = 0; jp < 4; ++jp) {
          int k0 = s * 16 + half * 8 + jp * 2;
          float f0 = W2[(size_t)k0 * TT + tile * 32 + l31];
          float f1 = W2[(size_t)(k0 + 1) * TT + tile * 32 + l31];
          wf.u[jp] = pkbf(f0, f1);
        }
        accl[tile] = __builtin_amdgcn_mfma_f32_32x32x16_bf16(
            ahf[s], wf.v, accl[tile], 0, 0, 0);
      }
      float bt = b2[tile * 32 + l31];
#pragma unroll
      for (int i = 0; i < 16; ++i) accl[tile][i] += bt;
    }

    float mrow[16];
#pragma unroll
    for (int r = 0; r < 16; ++r)
      mrow[r] = fmaxf(fmaxf(accl[0][r], accl[1][r]),
                      fmaxf(accl[2][r], accl[3][r]));
#pragma unroll
    for (int msk = 1; msk <= 16; msk <<= 1)
#pragma unroll
      for (int r = 0; r < 16; ++r)
        mrow[r] = fmaxf(mrow[r], __shfl_xor(mrow[r], msk, 64));
    float srow[16];
#pragma unroll
    for (int r = 0; r < 16; ++r) srow[r] = 0.f;
#pragma unroll
    for (int tile = 0; tile < 4; ++tile)
#pragma unroll
      for (int r = 0; r < 16; ++r) {
        float e = __expf(accl[tile][r] - mrow[r]);
        accl[tile][r] = e;
        srow[r] += e;
      }
#pragma unroll
    for (int msk = 1; msk <= 16; msk <<= 1)
#pragma unroll
      for (int r = 0; r < 16; ++r)
        srow[r] += __shfl_xor(srow[r], msk, 64);
#pragma unroll
    for (int r = 0; r < 16; ++r) srow[r] = 1.f / srow[r];

#pragma unroll
    for (int tile = 0; tile < 4; ++tile)
#pragma unroll
      for (int r = 0; r < 16; ++r) {
        int row = (r & 3) + 8 * (r >> 2) + 4 * half;
        attnB[(size_t)(b0 + row) * TT + tile * 32 + l31] =
            __float2half(accl[tile][r] * srow[r]);
      }

  } else if (blk < 384) {
    // ------- leaf softmax (1 tree) -> COMPACT fp16 B-frags ------------------
    float* lps = (float*)smem_raw;   // [128][12] f32 = 6144 B
    const int t0 = blk - 256;
#pragma unroll
    for (int rr = 0; rr < 2; ++rr) {
      int l = lane * 2 + rr;         // 0..127
      const float* row = lo + ((size_t)t0 * 128 + l) * CC;
      float v[CC];
      float m = -1e30f;
#pragma unroll
      for (int c = 0; c < CC; ++c) { v[c] = row[c]; m = fmaxf(m, v[c]); }
      float s = 0.f;
#pragma unroll
      for (int c = 0; c < CC; ++c) { v[c] = __expf(v[c] - m); s += v[c]; }
      float inv = 1.f / s;
      float* o = lps + l * 12;
#pragma unroll
      for (int c = 0; c < CC; ++c) o[c] = v[c] * inv;
    }
    __syncthreads();

    // layout: idx = tree*160 + s*20 + n*2 + hf  (uint4)
#pragma unroll
    for (int jj = 0; jj < 3; ++jj) {
      int idx = jj * 64 + lane;      // 0..191
      if (idx < 160) {
        int s = idx / 20, e = idx - s * 20;
        int n = e >> 1, hf = e & 1;
        unsigned int wd[4];
#pragma unroll
        for (int jp = 0; jp < 4; ++jp) {
          int l0 = s * 16 + hf * 8 + jp * 2;
          float f0 = lps[l0 * 12 + n];
          float f1 = lps[(l0 + 1) * 12 + n];
          wd[jp] = pkh(f0, f1);
        }
        ((uint4*)lpbG)[(size_t)t0 * 160 + idx] =
            make_uint4(wd[0], wd[1], wd[2], wd[3]);
      }
    }
  } else if (blk < 668) {
    // ------------- f32 -> bf16: x (256 blocks) / mask (28 blocks) -----------
    const float* src;
    unsigned short* dst;
    size_t base;
    if (blk < 640) { src = x;    dst = xbf; base = (size_t)(blk - 384) * 4096; }
    else           { src = mask; dst = mbf; base = (size_t)(blk - 640) * 4096; }
#pragma unroll
    for (int j = 0; j < 8; ++j) {
      size_t e = base + (size_t)j * 512 + (size_t)lane * 8;
      float4 a = *(const float4*)(src + e);
      float4 b = *(const float4*)(src + e + 4);
      *(short8*)(dst + e) = cvt8(a, b);
    }
  } else {
    // ------------- zero out (re-zeroed EVERY launch; atomics follow) --------
    const int base4 = (blk - 668) * 512;
#pragma unroll
    for (int j = 0; j < 8; ++j)
      ((float4*)out)[base4 + j * 64 + lane] = make_float4(0.f, 0.f, 0.f, 0.f);
  }
}

// -------- main: 2048 blocks = (bg2 0..63) x (tg4 0..31), 4 trees each -------
// LDS: zsl half[4][128][8] = 8192 | lpt uint4[640] = 10240  -> 18432 B
// launch_bounds(256,6): 6 blocks/CU = 24 waves/CU; VGPR cap ~84 (af in-loop
// keeps phase-1 live set ~70, no spill).
__global__ __launch_bounds__(256, 6) void main_kernel(
    const unsigned short* __restrict__ xbf, const unsigned short* __restrict__ mbf,
    const float* __restrict__ thr, const __half* __restrict__ attnB,
    const unsigned int* __restrict__ lpbG, float* __restrict__ out) {
  __shared__ __align__(16) char smem_raw[18432];
  const int tid = threadIdx.x;
  const int wv = tid >> 6, lane = tid & 63;
  const int half = lane >> 5, l31 = lane & 31;
  const int phys = blockIdx.x;
  const int bg2 = (phys & 7) * 8 + (phys >> 8);   // 0..63 (same-XCD chunks)
  const int tg4 = (phys >> 3) & 31;               // 0..31: trees tg4*4..+4
  const int bl = wv * 32 + l31;                   // own local row 0..127

  __half* zsl = (__half*)smem_raw;                // [4 tree][128 row][8]
  uint4* st4 = (uint4*)(smem_raw + 8192);         // lpt stage [640]

  // ---- early: issue lpt loads (reg-stage) + attn vec; hide under phase 1 ---
  const uint4* lpg = (const uint4*)lpbG + (size_t)tg4 * 640;
  uint4 stg0 = lpg[wv * 64 + lane];
  uint4 stg1 = lpg[(wv + 4) * 64 + lane];
  uint4 stg2 = make_uint4(0u, 0u, 0u, 0u);
  if (wv < 2) stg2 = lpg[(wv + 8) * 64 + lane];

  // attnB row = 128 halves = 32 uint2 (uint2 = 4 halves); group tg4 -> +tg4.
  // (R20 BUG was *64 + tg4*2: OOB for rows>=4096.)
  __half av[4];
  *(uint2*)av = ((const uint2*)attnB)[(size_t)(bg2 * 128 + bl) * 32 + tg4];

  // ==================== Phase 1: zs -> LDS (per-wave rows) ==================
  {
    const int m0 = tg4 * 28;
    short8 xf[8];
    const unsigned short* xr = xbf + (size_t)(bg2 * 128 + bl) * II + half * 8;
#pragma unroll
    for (int s = 0; s < 8; ++s) xf[s] = *(const short8*)(xr + s * 16);

    int mr = m0 + l31; if (mr > 895) mr = 895;   // A-pad rows (only tg4=31)
    const unsigned short* mrow = mbf + (size_t)mr * II + half * 8;

    floatx16 acc;
#pragma unroll
    for (int i = 0; i < 16; ++i) acc[i] = 0.f;
    // af loaded in-loop: compiler hoists ahead only up to the VGPR cap
#pragma unroll
    for (int s = 0; s < 8; ++s) {
      short8 af = *(const short8*)(mrow + s * 16);
      acc = __builtin_amdgcn_mfma_f32_32x32x16_bf16(af, xf[s], acc, 0, 0, 0);
    }

#pragma unroll
    for (int r = 0; r < 16; ++r) {
      int row = (r & 3) + 8 * (r >> 2) + 4 * half;   // m-local 0..31
      if (row < 28) {
        int tl = row / 7;
        int d = row - tl * 7;
        float z = acc[r] - thr[m0 + row];
        float o = 0.5f * (z / (1.f + fabsf(z)) + 1.f);
        zsl[((tl * 128) + bl) * 8 + d] = __float2half(o);
      }
    }
  }

  // ---- complete lpt staging, then one barrier ------------------------------
  st4[wv * 64 + lane] = stg0;
  st4[(wv + 4) * 64 + lane] = stg1;
  if (wv < 2) st4[(wv + 8) * 64 + lane] = stg2;
  __syncthreads();

  // ==================== Phase 2: contraction (4 trees) ======================
  {
    const uint4* zsl4 = (const uint4*)smem_raw;

    floatx16 acc;
#pragma unroll
    for (int i = 0; i < 16; ++i) acc[i] = 0.f;

#pragma unroll
    for (int it = 0; it < 4; ++it) {
      uint4 bf[8];
#pragma unroll
      for (int s = 0; s < 8; ++s)
        bf[s] = (l31 < CC) ? st4[(it * 8 + s) * 20 + l31 * 2 + half]
                           : make_uint4(0u, 0u, 0u, 0u);
      uint4 sv = zsl4[it * 128 + bl];

      const __half* sh = (const __half*)&sv;
      float s0 = __half2float(sh[0]), s1 = __half2float(sh[1]);
      float s2 = __half2float(sh[2]), s3 = __half2float(sh[3]);
      float s4 = __half2float(sh[4]), s5 = __half2float(sh[5]);
      float s6 = __half2float(sh[6]);
      float A  = __half2float(av[it]);

      float s0c = 1.f - s0, s1c = 1.f - s1, s2c = 1.f - s2;
      float t0 = s0 * s1, t1 = s0c * s1, t2 = s0 * s1c, t3 = s0c * s1c;
      float pl[8];
      pl[0] = t0 * s2;  pl[1] = t1 * s2;  pl[2] = t2 * s2;  pl[3] = t3 * s2;
      pl[4] = t0 * s2c; pl[5] = t1 * s2c; pl[6] = t2 * s2c; pl[7] = t3 * s2c;
      float sel3 = half ? (1.f - s3) : s3;
      float Af = A * sel3;
      float s4c = 1.f - s4, s5c = 1.f - s5;
      float as6 = Af * s6, as6c = Af * (1.f - s6);
      float u0 = s4 * s5, u1 = s4c * s5, u2 = s4 * s5c, u3 = s4c * s5c;
      float wv8[8];
      wv8[0] = u0 * as6;  wv8[1] = u1 * as6;
      wv8[2] = u2 * as6;  wv8[3] = u3 * as6;
      wv8[4] = u0 * as6c; wv8[5] = u1 * as6c;
      wv8[6] = u2 * as6c; wv8[7] = u3 * as6c;
      __half2 pl2[4];
#pragma unroll
      for (int jp = 0; jp < 4; ++jp)
        pl2[jp] = __float22half2_rn(make_float2(pl[jp * 2], pl[jp * 2 + 1]));

#pragma unroll
      for (int s = 0; s < 8; ++s) {
        union { short8 v; __half2 h[4]; } a0;
        __half2 w2 = __half2half2(__float2half(wv8[s]));
#pragma unroll
        for (int jp = 0; jp < 4; ++jp) a0.h[jp] = __hmul2(pl2[jp], w2);
        acc = __builtin_amdgcn_mfma_f32_32x32x16_f16(
            a0.v, *(const short8*)&bf[s], acc, 0, 0, 0);
      }
    }

    // -------- epilogue: red overlays zsl (barrier both sides) --------------
    __syncthreads();   // all zsl/st4 reads done before overlay write
    float* red = (float*)smem_raw;   // [128][10] f32 = 5120 B
    if (l31 < CC) {
#pragma unroll
      for (int r = 0; r < 16; ++r) {
        int row = (r & 3) + 8 * (r >> 2) + 4 * half;
        red[(wv * 32 + row) * 10 + l31] = acc[r];
      }
    }
    __syncthreads();
#pragma unroll
    for (int j = 0; j < 5; ++j) {
      int idx = tid + 256 * j;   // 0..1279
      atomicAdd(out + (size_t)bg2 * 1280 + idx, red[idx]);
    }
  }
}

// ---------------------------------------------------------------------------
extern "C" void kernel_launch(void* const* d_in, const int* in_sizes, int n_in,
                              void* d_out, int out_size, void* d_ws, size_t ws_size,
                              hipStream_t stream) {
  const float* x    = (const float*)d_in[0];
  const float* mask = (const float*)d_in[1];
  const float* thr  = (const float*)d_in[2];
  const float* lo   = (const float*)d_in[3];
  const float* W1   = (const float*)d_in[4];
  const float* b1   = (const float*)d_in[5];
  const float* W2   = (const float*)d_in[6];
  const float* b2   = (const float*)d_in[7];
  float* out = (float*)d_out;
  float* ws  = (float*)d_ws;

  __half*         attnB = (__half*)ws;
  unsigned int*   LPb   = (unsigned int*)(ws + OFF_LPB);
  unsigned short* xbf   = (unsigned short*)(ws + OFF_XBF);
  unsigned short* mbf   = (unsigned short*)(ws + OFF_MBF);

  prep_kernel<<<708, 64, 0, stream>>>(x, mask, lo, W1, b1, W2, b2,
                                      attnB, LPb, xbf, mbf, out);
  main_kernel<<<2048, 256, 0, stream>>>(xbf, mbf, thr, attnB, LPb, out);
}